// Round 9
// baseline (413.080 us; speedup 1.0000x reference)
//
#include <hip/hip_runtime.h>
#include <hip/hip_fp16.h>
#include <math.h>

#define N_NODES 50000
#define N_EDGES 800000
#define ET (N_EDGES + N_NODES)   // edges + self-loops
#define IN_DIM 128
#define HID 64
#define HEADS 4
#define C1 (HEADS * HID)         // 256
#define OUT_DIM 128
#define NEG_SLOPE 0.2f
#define MTILES 3125              // 50000 / 16 row-tiles
#define SCAN_B 1024
#define NSCB 49                  // ceil(50000/1024)

typedef _Float16 h8 __attribute__((ext_vector_type(8)));
typedef float f4 __attribute__((ext_vector_type(4)));

__device__ __forceinline__ float leaky(float v) { return v > 0.0f ? v : NEG_SLOPE * v; }
__device__ __forceinline__ float elu(float v) { return v > 0.0f ? v : expm1f(v); }

// ================= fused prep: x->fp16, weight transpose->fp16, dst histogram =================
__global__ void prep_kernel(const float* __restrict__ x, const float* __restrict__ W1,
                            const float* __restrict__ W2, const int* __restrict__ dst,
                            __half* __restrict__ xh, __half* __restrict__ w1t,
                            __half* __restrict__ w2t, int* __restrict__ cnt) {
    const int tid = blockIdx.x * blockDim.x + threadIdx.x;
    const int np = gridDim.x * blockDim.x;
    for (int i = tid; i < N_NODES * IN_DIM / 4; i += np) {
        float4 v = ((const float4*)x)[i];
        ((__half2*)xh)[2 * i]     = __floats2half2_rn(v.x, v.y);
        ((__half2*)xh)[2 * i + 1] = __floats2half2_rn(v.z, v.w);
    }
    for (int i = tid; i < IN_DIM * C1; i += np) {
        int k1 = i >> 8, n1 = i & 255;
        w1t[n1 * IN_DIM + k1] = __float2half(W1[i]);
        int k2 = i >> 7, n2 = i & 127;
        w2t[n2 * C1 + k2] = __float2half(W2[i]);
    }
    for (int i = tid; i < ET; i += np) {
        int d = (i < N_EDGES) ? dst[i] : i - N_EDGES;
        atomicAdd(&cnt[d], 1);
    }
}

// ================= CSR scan + scatter =================
__global__ void scan_local(const int* __restrict__ cnt, int* __restrict__ lscan,
                           int* __restrict__ bsum) {
    __shared__ int wsum[16];
    const int t = threadIdx.x, lane = t & 63, wv = t >> 6;
    int idx = blockIdx.x * SCAN_B + t;
    int v = (idx < N_NODES) ? cnt[idx] : 0;
    int sc = v;
#pragma unroll
    for (int o = 1; o < 64; o <<= 1) {
        int u = __shfl_up(sc, o);
        if (lane >= o) sc += u;
    }
    if (lane == 63) wsum[wv] = sc;
    __syncthreads();
    if (t == 0) {
        int run = 0;
#pragma unroll
        for (int w = 0; w < 16; ++w) { int s = wsum[w]; wsum[w] = run; run += s; }
        bsum[blockIdx.x] = run;
    }
    __syncthreads();
    if (idx < N_NODES) lscan[idx] = sc + wsum[wv];  // inclusive within block
}

__global__ void scan_bsum(int* __restrict__ bsum) {  // 1 block, 64 thr
    const int t = threadIdx.x;
    int v = (t < NSCB) ? bsum[t] : 0;
    int sc = v;
#pragma unroll
    for (int o = 1; o < 64; o <<= 1) {
        int u = __shfl_up(sc, o);
        if (t >= o) sc += u;
    }
    if (t < NSCB) bsum[t] = sc - v;  // exclusive
}

__global__ void scan_final(const int* __restrict__ cnt, const int* __restrict__ lscan,
                           const int* __restrict__ bsum, int* __restrict__ rp,
                           int* __restrict__ cursor) {
    int idx = blockIdx.x * SCAN_B + threadIdx.x;
    if (idx == 0) rp[0] = 0;
    if (idx >= N_NODES) return;
    int inc = lscan[idx] + bsum[idx >> 10];
    rp[idx + 1] = inc;
    cursor[idx] = inc - cnt[idx];
}

__global__ void scatter_kernel(const int* __restrict__ src, const int* __restrict__ dst,
                               int* __restrict__ cursor, int* __restrict__ col_src) {
    int i = blockIdx.x * blockDim.x + threadIdx.x;
    if (i >= ET) return;
    int s, d;
    if (i < N_EDGES) { s = src[i]; d = dst[i]; } else { s = d = i - N_EDGES; }
    int pos = atomicAdd(&cursor[d], 1);
    col_src[pos] = s;
}

// ================= GEMM1 (MFMA fp16) + fused attention dots =================
__global__ __launch_bounds__(256) void gemm1_mfma(
        const __half* __restrict__ xh, const __half* __restrict__ w1t,
        const float* __restrict__ aws, const float* __restrict__ awd,
        __half* __restrict__ h, float* __restrict__ as1, float* __restrict__ ad1) {
    const int tile = blockIdx.x * 4 + (threadIdx.x >> 6);
    if (tile >= MTILES) return;
    const int lane = threadIdx.x & 63;
    const int m0 = tile * 16, lm = lane & 15, lq = lane >> 4;
    h8 afrag[4];
    const h8* arow = (const h8*)(xh + (size_t)(m0 + lm) * IN_DIM + lq * 8);
#pragma unroll
    for (int kt = 0; kt < 4; ++kt) afrag[kt] = arow[kt * 4];
    f4 acc[16];
#pragma unroll
    for (int nt = 0; nt < 16; ++nt) acc[nt] = (f4){0.f, 0.f, 0.f, 0.f};
#pragma unroll
    for (int nt = 0; nt < 16; ++nt) {
        const h8* brow = (const h8*)(w1t + (size_t)(nt * 16 + lm) * IN_DIM + lq * 8);
#pragma unroll
        for (int kt = 0; kt < 4; ++kt)
            acc[nt] = __builtin_amdgcn_mfma_f32_16x16x32_f16(afrag[kt], brow[kt * 4],
                                                             acc[nt], 0, 0, 0);
    }
    float sS[4][4] = {{0.f}}, sD[4][4] = {{0.f}};
#pragma unroll
    for (int nt = 0; nt < 16; ++nt) {
        int col = nt * 16 + lm;
        float wa = aws[col], wd = awd[col];
        int hd = nt >> 2;
#pragma unroll
        for (int r = 0; r < 4; ++r) {
            float v = acc[nt][r];
            h[(size_t)(m0 + lq * 4 + r) * C1 + col] = __float2half(v);
            sS[hd][r] += v * wa;
            sD[hd][r] += v * wd;
        }
    }
#pragma unroll
    for (int o = 1; o < 16; o <<= 1) {
#pragma unroll
        for (int hd = 0; hd < 4; ++hd)
#pragma unroll
            for (int r = 0; r < 4; ++r) {
                sS[hd][r] += __shfl_xor(sS[hd][r], o);
                sD[hd][r] += __shfl_xor(sD[hd][r], o);
            }
    }
    if (lm == 0) {
#pragma unroll
        for (int r = 0; r < 4; ++r) {
            int row = m0 + lq * 4 + r;
            ((float4*)as1)[row] = make_float4(sS[0][r], sS[1][r], sS[2][r], sS[3][r]);
            ((float4*)ad1)[row] = make_float4(sD[0][r], sD[1][r], sD[2][r], sD[3][r]);
        }
    }
}

// ================= GEMM2 (MFMA fp16) + fused attention dots (1 head) =================
__global__ __launch_bounds__(256) void gemm2_mfma(
        const __half* __restrict__ ah, const __half* __restrict__ w2t,
        const float* __restrict__ aws, const float* __restrict__ awd,
        __half* __restrict__ h, float* __restrict__ as2, float* __restrict__ ad2) {
    const int tile = blockIdx.x * 4 + (threadIdx.x >> 6);
    if (tile >= MTILES) return;
    const int lane = threadIdx.x & 63;
    const int m0 = tile * 16, lm = lane & 15, lq = lane >> 4;
    h8 afrag[8];
    const h8* arow = (const h8*)(ah + (size_t)(m0 + lm) * C1 + lq * 8);
#pragma unroll
    for (int kt = 0; kt < 8; ++kt) afrag[kt] = arow[kt * 4];
    f4 acc[8];
#pragma unroll
    for (int nt = 0; nt < 8; ++nt) acc[nt] = (f4){0.f, 0.f, 0.f, 0.f};
#pragma unroll
    for (int nt = 0; nt < 8; ++nt) {
        const h8* brow = (const h8*)(w2t + (size_t)(nt * 16 + lm) * C1 + lq * 8);
#pragma unroll
        for (int kt = 0; kt < 8; ++kt)
            acc[nt] = __builtin_amdgcn_mfma_f32_16x16x32_f16(afrag[kt], brow[kt * 4],
                                                             acc[nt], 0, 0, 0);
    }
    float sS[4] = {0.f, 0.f, 0.f, 0.f}, sD[4] = {0.f, 0.f, 0.f, 0.f};
#pragma unroll
    for (int nt = 0; nt < 8; ++nt) {
        int col = nt * 16 + lm;
        float wa = aws[col], wd = awd[col];
#pragma unroll
        for (int r = 0; r < 4; ++r) {
            float v = acc[nt][r];
            h[(size_t)(m0 + lq * 4 + r) * OUT_DIM + col] = __float2half(v);
            sS[r] += v * wa;
            sD[r] += v * wd;
        }
    }
#pragma unroll
    for (int o = 1; o < 16; o <<= 1) {
#pragma unroll
        for (int r = 0; r < 4; ++r) {
            sS[r] += __shfl_xor(sS[r], o);
            sD[r] += __shfl_xor(sD[r], o);
        }
    }
    if (lm == 0) {
#pragma unroll
        for (int r = 0; r < 4; ++r) {
            int row = m0 + lq * 4 + r;
            as2[row] = sS[r];
            ad2[row] = sD[r];
        }
    }
}

// ================= fused softmax + aggregate, layer 1 — XCD-split by head =================
// Each block handles ONE feature-quarter (= one head, 64 feats = 128 B) of 4 nodes.
// blockIdx%8 ~ XCD (round-robin): XCDs {2q, 2q+1} process only quarter q, so each
// XCD's L2 sees a 6.4 MB h1 slice instead of 25.6 MB.
// Wave layout: 8 rows per dwordx4 wave-load (8 lanes x 16 B = 128 B per row).
__global__ __launch_bounds__(256) void aggregate1_fused(
        const int* __restrict__ rp, const int* __restrict__ cs,
        const __half* __restrict__ h1h, const float* __restrict__ as1,
        const float* __restrict__ ad1, const float* __restrict__ b1,
        __half* __restrict__ out1h) {
    __shared__ int2 stg[4][64];      // [wave][edge] = {row byte offset, alpha bits}
    const int b = blockIdx.x;
    const int xcd = b & 7, q = xcd >> 1;          // quarter / head
    const int ng = (b >> 3) * 2 + (xcd & 1);      // node group [0,12500)
    const int wv = threadIdx.x >> 6, lane = threadIdx.x & 63;
    const int d = ng * 4 + wv;
    const int e0 = rp[d], deg = rp[d + 1] - e0;   // deg >= 1 (self-loop)
    const float adv = ad1[d * 4 + q];
    const int g = lane >> 3, li = lane & 7;       // 8 row-groups x 8 lanes-per-row
    const int lbyte = li * 16;                    // 8 fp16 = 16 B; 8 lanes cover 128 B
    const char* hbase = (const char*)h1h + q * 128;  // quarter offset within row
    float acc[8] = {0.f, 0.f, 0.f, 0.f, 0.f, 0.f, 0.f, 0.f};
    float dsum = 0.f;
    for (int c0 = 0; c0 < deg; c0 += 64) {
        const int clen = min(64, deg - c0);
        int idx = c0 + lane;
        bool valid = idx < deg;
        int s = valid ? cs[e0 + idx] : 0;
        float av = as1[s * 4 + q];
        float x = valid ? expf(leaky(av + adv)) : 0.f;
        stg[wv][lane] = make_int2(valid ? (s << 9) : 0, __float_as_int(x));
        dsum += x;
        __builtin_amdgcn_wave_barrier();  // DS in-order per wave; fence compiler reordering
        for (int j = 0; j < clen; j += 8) {
            int2 p = stg[wv][j + g];      // overrun groups read alpha=0 entries (harmless)
            h8 v = *(const h8*)(hbase + p.x + lbyte);
            float w = __int_as_float(p.y);
#pragma unroll
            for (int f = 0; f < 8; ++f) acc[f] += (float)v[f] * w;
        }
        __builtin_amdgcn_wave_barrier();
    }
    // reduce partial sums across the 8 row-groups (lanes with same li share feats)
#pragma unroll
    for (int f = 0; f < 8; ++f) {
        acc[f] += __shfl_xor(acc[f], 8);
        acc[f] += __shfl_xor(acc[f], 16);
        acc[f] += __shfl_xor(acc[f], 32);
    }
    // denominator over all staged edges
#pragma unroll
    for (int o = 32; o > 0; o >>= 1) dsum += __shfl_xor(dsum, o);
    if (g == 0) {  // lanes 0-7 write the quarter (8 x 16 B = 128 B)
        float inv = 1.0f / (dsum + 1e-16f);
        float4 bA = ((const float4*)b1)[q * 16 + li * 2];
        float4 bB = ((const float4*)b1)[q * 16 + li * 2 + 1];
        h8 o;
        o[0] = (_Float16)elu(acc[0] * inv + bA.x);
        o[1] = (_Float16)elu(acc[1] * inv + bA.y);
        o[2] = (_Float16)elu(acc[2] * inv + bA.z);
        o[3] = (_Float16)elu(acc[3] * inv + bA.w);
        o[4] = (_Float16)elu(acc[4] * inv + bB.x);
        o[5] = (_Float16)elu(acc[5] * inv + bB.y);
        o[6] = (_Float16)elu(acc[6] * inv + bB.z);
        o[7] = (_Float16)elu(acc[7] * inv + bB.w);
        *(h8*)((char*)out1h + (size_t)d * 512 + q * 128 + lbyte) = o;
    }
}

// ================= fused softmax + aggregate + bias + L2-normalize, layer 2 =================
// wave per node; 4 rows per dwordx4 load (16 lanes x 16 B per row).
__global__ __launch_bounds__(256) void aggregate2_fused(
        const int* __restrict__ rp, const int* __restrict__ cs,
        const __half* __restrict__ h2h, const float* __restrict__ as2,
        const float* __restrict__ ad2, const float* __restrict__ b2,
        float* __restrict__ out) {
    __shared__ int2 stg[4][64];      // [wave][edge] = {row byte offset, alpha bits}
    const int wv = threadIdx.x >> 6, lane = threadIdx.x & 63;
    const int d = blockIdx.x * 4 + wv;
    const int e0 = rp[d], deg = rp[d + 1] - e0;
    const float adv = ad2[d];
    const int q = lane >> 4, li = lane & 15;
    const int lbyte = li * 16;       // 8 fp16
    const char* hbase = (const char*)h2h;
    float acc[8] = {0.f, 0.f, 0.f, 0.f, 0.f, 0.f, 0.f, 0.f};
    float dsum = 0.f;
    for (int c0 = 0; c0 < deg; c0 += 64) {
        const int clen = min(64, deg - c0);
        int idx = c0 + lane;
        bool valid = idx < deg;
        int s = valid ? cs[e0 + idx] : 0;
        float x = valid ? expf(leaky(as2[s] + adv)) : 0.f;
        stg[wv][lane] = make_int2(valid ? (s << 8) : 0, __float_as_int(x));  // row = 256 B
        dsum += x;
        __builtin_amdgcn_wave_barrier();
        int j = 0;
        for (; j + 8 <= clen; j += 8) {
            int2 p0 = stg[wv][j + q];
            int2 p1 = stg[wv][j + 4 + q];
            h8 v0 = *(const h8*)(hbase + p0.x + lbyte);
            h8 v1 = *(const h8*)(hbase + p1.x + lbyte);
            float w0 = __int_as_float(p0.y), w1 = __int_as_float(p1.y);
#pragma unroll
            for (int f = 0; f < 8; ++f) acc[f] += (float)v0[f] * w0;
#pragma unroll
            for (int f = 0; f < 8; ++f) acc[f] += (float)v1[f] * w1;
        }
        for (; j < clen; j += 4) {
            int2 p0 = stg[wv][j + q];
            h8 v0 = *(const h8*)(hbase + p0.x + lbyte);
            float w0 = __int_as_float(p0.y);
#pragma unroll
            for (int f = 0; f < 8; ++f) acc[f] += (float)v0[f] * w0;
        }
        __builtin_amdgcn_wave_barrier();
    }
#pragma unroll
    for (int f = 0; f < 8; ++f) {
        acc[f] += __shfl_xor(acc[f], 16);
        acc[f] += __shfl_xor(acc[f], 32);
    }
#pragma unroll
    for (int o = 32; o > 0; o >>= 1) dsum += __shfl_xor(dsum, o);
    if (q == 0) {
        float inv = 1.0f / (dsum + 1e-16f);
        float4 bA = ((const float4*)b2)[li * 2];
        float4 bB = ((const float4*)b2)[li * 2 + 1];
        float v0 = acc[0] * inv + bA.x, v1 = acc[1] * inv + bA.y;
        float v2 = acc[2] * inv + bA.z, v3 = acc[3] * inv + bA.w;
        float v4 = acc[4] * inv + bB.x, v5 = acc[5] * inv + bB.y;
        float v6 = acc[6] * inv + bB.z, v7 = acc[7] * inv + bB.w;
        float ss = v0 * v0 + v1 * v1 + v2 * v2 + v3 * v3 +
                   v4 * v4 + v5 * v5 + v6 * v6 + v7 * v7;
#pragma unroll
        for (int o = 1; o < 16; o <<= 1) ss += __shfl_xor(ss, o);  // lanes 0-15 group
        float sc = 1.0f / fmaxf(sqrtf(ss), 1e-12f);
        float4* orow = (float4*)((char*)out + (size_t)d * 512 + li * 32);
        orow[0] = make_float4(v0 * sc, v1 * sc, v2 * sc, v3 * sc);
        orow[1] = make_float4(v4 * sc, v5 * sc, v6 * sc, v7 * sc);
    }
}

extern "C" void kernel_launch(void* const* d_in, const int* in_sizes, int n_in,
                              void* d_out, int out_size, void* d_ws, size_t ws_size,
                              hipStream_t stream) {
    const float* x     = (const float*)d_in[0];
    const int*   edge  = (const int*)d_in[1];
    const int*   src   = edge;
    const int*   dst   = edge + N_EDGES;
    const float* W1    = (const float*)d_in[2];
    const float* aw_s1 = (const float*)d_in[3];
    const float* aw_d1 = (const float*)d_in[4];
    const float* b1    = (const float*)d_in[5];
    const float* W2    = (const float*)d_in[6];
    const float* aw_s2 = (const float*)d_in[7];
    const float* aw_d2 = (const float*)d_in[8];
    const float* b2    = (const float*)d_in[9];
    float* out = (float*)d_out;

    // ---- workspace layout: small control buffers first, big streams last ----
    char* ws = (char*)d_ws;
    size_t off = 0;
    auto alloc = [&](size_t bytes) {
        void* p = ws + off;
        off += (bytes + 255) & ~(size_t)255;
        return p;
    };
    int*    col_src = (int*)alloc((size_t)ET * 4);                  // 3.4 MB
    int*    rp     = (int*)alloc((size_t)(N_NODES + 1) * 4);
    int*    cursor = (int*)alloc((size_t)N_NODES * 4);
    int*    cnt    = (int*)alloc((size_t)N_NODES * 4);
    int*    lscan  = (int*)alloc((size_t)NSCB * SCAN_B * 4);
    int*    bsum   = (int*)alloc((size_t)NSCB * 4);
    float*  as1    = (float*)alloc((size_t)N_NODES * HEADS * 4);
    float*  ad1    = (float*)alloc((size_t)N_NODES * HEADS * 4);
    float*  as2    = (float*)alloc((size_t)N_NODES * 4);
    float*  ad2    = (float*)alloc((size_t)N_NODES * 4);
    __half* w1t    = (__half*)alloc((size_t)IN_DIM * C1 * 2);
    __half* w2t    = (__half*)alloc((size_t)C1 * OUT_DIM * 2);
    __half* xh     = (__half*)alloc((size_t)N_NODES * IN_DIM * 2);  // 12.8 MB
    __half* h1h    = (__half*)alloc((size_t)N_NODES * C1 * 2);      // 25.6 MB (reused as h2h)
    __half* out1h  = (__half*)alloc((size_t)N_NODES * C1 * 2);      // 25.6 MB
    __half* h2h    = h1h;  // layer-1 projection dead after aggregate1
    const size_t ws_used = off;

    // Reproduce call-1 initial state every call (harness re-poisons ws with 0xAA).
    hipMemsetAsync(d_ws, 0, ws_used, stream);

    const int egrid = (ET + 255) / 256;

    // ---- prep (x->fp16 + weight transpose + histogram) + CSR build ----
    prep_kernel<<<2048, 256, 0, stream>>>(x, W1, W2, dst, xh, w1t, w2t, cnt);
    scan_local<<<NSCB, SCAN_B, 0, stream>>>(cnt, lscan, bsum);
    scan_bsum<<<1, 64, 0, stream>>>(bsum);
    scan_final<<<NSCB, SCAN_B, 0, stream>>>(cnt, lscan, bsum, rp, cursor);
    scatter_kernel<<<egrid, 256, 0, stream>>>(src, dst, cursor, col_src);

    // ---- layer 1 ----
    gemm1_mfma<<<(MTILES + 3) / 4, 256, 0, stream>>>(xh, w1t, aw_s1, aw_d1, h1h, as1, ad1);
    // 4 quarters x 12500 node-groups; blockIdx%8 ~ XCD, quarter = (blockIdx%8)>>1
    aggregate1_fused<<<N_NODES, 256, 0, stream>>>(rp, col_src, h1h, as1, ad1, b1, out1h);

    // ---- layer 2 ----
    gemm2_mfma<<<(MTILES + 3) / 4, 256, 0, stream>>>(out1h, w2t, aw_s2, aw_d2, h2h, as2, ad2);
    aggregate2_fused<<<N_NODES / 4, 256, 0, stream>>>(rp, col_src, h2h, as2, ad2, b2, out);
}

// Round 10
// 363.428 us; speedup vs baseline: 1.1366x; 1.1366x over previous
//
#include <hip/hip_runtime.h>
#include <hip/hip_fp16.h>
#include <math.h>

#define N_NODES 50000
#define N_EDGES 800000
#define ET (N_EDGES + N_NODES)   // edges + self-loops
#define IN_DIM 128
#define HID 64
#define HEADS 4
#define C1 (HEADS * HID)         // 256
#define OUT_DIM 128
#define NEG_SLOPE 0.2f
#define MTILES 3125              // 50000 / 16 row-tiles
#define SCAN_B 1024
#define NSCB 49                  // ceil(50000/1024)

typedef _Float16 h8 __attribute__((ext_vector_type(8)));
typedef float f4 __attribute__((ext_vector_type(4)));

__device__ __forceinline__ float leaky(float v) { return v > 0.0f ? v : NEG_SLOPE * v; }
__device__ __forceinline__ float elu(float v) { return v > 0.0f ? v : expm1f(v); }

// ================= prep: weight transpose->fp16 + dst histogram =================
__global__ void prep_kernel(const float* __restrict__ W1, const float* __restrict__ W2,
                            const int* __restrict__ dst, __half* __restrict__ w1t,
                            __half* __restrict__ w2t, int* __restrict__ cnt) {
    const int tid = blockIdx.x * blockDim.x + threadIdx.x;
    const int np = gridDim.x * blockDim.x;
    for (int i = tid; i < IN_DIM * C1; i += np) {
        int k1 = i >> 8, n1 = i & 255;
        w1t[n1 * IN_DIM + k1] = __float2half(W1[i]);
        int k2 = i >> 7, n2 = i & 127;
        w2t[n2 * C1 + k2] = __float2half(W2[i]);
    }
    for (int i = tid; i < ET; i += np) {
        int d = (i < N_EDGES) ? dst[i] : i - N_EDGES;
        atomicAdd(&cnt[d], 1);
    }
}

// ================= CSR scan + scatter =================
__global__ void scan_local(const int* __restrict__ cnt, int* __restrict__ lscan,
                           int* __restrict__ bsum) {
    __shared__ int wsum[16];
    const int t = threadIdx.x, lane = t & 63, wv = t >> 6;
    int idx = blockIdx.x * SCAN_B + t;
    int v = (idx < N_NODES) ? cnt[idx] : 0;
    int sc = v;
#pragma unroll
    for (int o = 1; o < 64; o <<= 1) {
        int u = __shfl_up(sc, o);
        if (lane >= o) sc += u;
    }
    if (lane == 63) wsum[wv] = sc;
    __syncthreads();
    if (t == 0) {
        int run = 0;
#pragma unroll
        for (int w = 0; w < 16; ++w) { int s = wsum[w]; wsum[w] = run; run += s; }
        bsum[blockIdx.x] = run;
    }
    __syncthreads();
    if (idx < N_NODES) lscan[idx] = sc + wsum[wv];  // inclusive within block
}

__global__ void scan_bsum(int* __restrict__ bsum) {  // 1 block, 64 thr
    const int t = threadIdx.x;
    int v = (t < NSCB) ? bsum[t] : 0;
    int sc = v;
#pragma unroll
    for (int o = 1; o < 64; o <<= 1) {
        int u = __shfl_up(sc, o);
        if (t >= o) sc += u;
    }
    if (t < NSCB) bsum[t] = sc - v;  // exclusive
}

__global__ void scan_final(const int* __restrict__ cnt, const int* __restrict__ lscan,
                           const int* __restrict__ bsum, int* __restrict__ rp,
                           int* __restrict__ cursor) {
    int idx = blockIdx.x * SCAN_B + threadIdx.x;
    if (idx == 0) rp[0] = 0;
    if (idx >= N_NODES) return;
    int inc = lscan[idx] + bsum[idx >> 10];
    rp[idx + 1] = inc;
    cursor[idx] = inc - cnt[idx];
}

__global__ void scatter_kernel(const int* __restrict__ src, const int* __restrict__ dst,
                               int* __restrict__ cursor, int* __restrict__ col_src) {
    int i = blockIdx.x * blockDim.x + threadIdx.x;
    if (i >= ET) return;
    int s, d;
    if (i < N_EDGES) { s = src[i]; d = dst[i]; } else { s = d = i - N_EDGES; }
    int pos = atomicAdd(&cursor[d], 1);
    col_src[pos] = s;
}

// ================= GEMM1 (MFMA fp16) + fused attention dots =================
// A read directly from fp32 x, converted to fp16 fragments in-register.
__global__ __launch_bounds__(256) void gemm1_mfma(
        const float* __restrict__ x, const __half* __restrict__ w1t,
        const float* __restrict__ aws, const float* __restrict__ awd,
        __half* __restrict__ h, float* __restrict__ as1, float* __restrict__ ad1) {
    const int tile = blockIdx.x * 4 + (threadIdx.x >> 6);
    if (tile >= MTILES) return;
    const int lane = threadIdx.x & 63;
    const int m0 = tile * 16, lm = lane & 15, lq = lane >> 4;
    h8 afrag[4];
    const float4* xrow = (const float4*)(x + (size_t)(m0 + lm) * IN_DIM + lq * 8);
#pragma unroll
    for (int kt = 0; kt < 4; ++kt) {
        float4 a = xrow[kt * 8];
        float4 b = xrow[kt * 8 + 1];
        union { h8 v; __half2 p[4]; } u;
        u.p[0] = __floats2half2_rn(a.x, a.y);
        u.p[1] = __floats2half2_rn(a.z, a.w);
        u.p[2] = __floats2half2_rn(b.x, b.y);
        u.p[3] = __floats2half2_rn(b.z, b.w);
        afrag[kt] = u.v;
    }
    f4 acc[16];
#pragma unroll
    for (int nt = 0; nt < 16; ++nt) acc[nt] = (f4){0.f, 0.f, 0.f, 0.f};
#pragma unroll
    for (int nt = 0; nt < 16; ++nt) {
        const h8* brow = (const h8*)(w1t + (size_t)(nt * 16 + lm) * IN_DIM + lq * 8);
#pragma unroll
        for (int kt = 0; kt < 4; ++kt)
            acc[nt] = __builtin_amdgcn_mfma_f32_16x16x32_f16(afrag[kt], brow[kt * 4],
                                                             acc[nt], 0, 0, 0);
    }
    float sS[4][4] = {{0.f}}, sD[4][4] = {{0.f}};
#pragma unroll
    for (int nt = 0; nt < 16; ++nt) {
        int col = nt * 16 + lm;
        float wa = aws[col], wd = awd[col];
        int hd = nt >> 2;
#pragma unroll
        for (int r = 0; r < 4; ++r) {
            float v = acc[nt][r];
            h[(size_t)(m0 + lq * 4 + r) * C1 + col] = __float2half(v);
            sS[hd][r] += v * wa;
            sD[hd][r] += v * wd;
        }
    }
#pragma unroll
    for (int o = 1; o < 16; o <<= 1) {
#pragma unroll
        for (int hd = 0; hd < 4; ++hd)
#pragma unroll
            for (int r = 0; r < 4; ++r) {
                sS[hd][r] += __shfl_xor(sS[hd][r], o);
                sD[hd][r] += __shfl_xor(sD[hd][r], o);
            }
    }
    if (lm == 0) {
#pragma unroll
        for (int r = 0; r < 4; ++r) {
            int row = m0 + lq * 4 + r;
            ((float4*)as1)[row] = make_float4(sS[0][r], sS[1][r], sS[2][r], sS[3][r]);
            ((float4*)ad1)[row] = make_float4(sD[0][r], sD[1][r], sD[2][r], sD[3][r]);
        }
    }
}

// ================= GEMM2 (MFMA fp16) + fused attention dots (1 head) =================
__global__ __launch_bounds__(256) void gemm2_mfma(
        const __half* __restrict__ ah, const __half* __restrict__ w2t,
        const float* __restrict__ aws, const float* __restrict__ awd,
        __half* __restrict__ h, float* __restrict__ as2, float* __restrict__ ad2) {
    const int tile = blockIdx.x * 4 + (threadIdx.x >> 6);
    if (tile >= MTILES) return;
    const int lane = threadIdx.x & 63;
    const int m0 = tile * 16, lm = lane & 15, lq = lane >> 4;
    h8 afrag[8];
    const h8* arow = (const h8*)(ah + (size_t)(m0 + lm) * C1 + lq * 8);
#pragma unroll
    for (int kt = 0; kt < 8; ++kt) afrag[kt] = arow[kt * 4];
    f4 acc[8];
#pragma unroll
    for (int nt = 0; nt < 8; ++nt) acc[nt] = (f4){0.f, 0.f, 0.f, 0.f};
#pragma unroll
    for (int nt = 0; nt < 8; ++nt) {
        const h8* brow = (const h8*)(w2t + (size_t)(nt * 16 + lm) * C1 + lq * 8);
#pragma unroll
        for (int kt = 0; kt < 8; ++kt)
            acc[nt] = __builtin_amdgcn_mfma_f32_16x16x32_f16(afrag[kt], brow[kt * 4],
                                                             acc[nt], 0, 0, 0);
    }
    float sS[4] = {0.f, 0.f, 0.f, 0.f}, sD[4] = {0.f, 0.f, 0.f, 0.f};
#pragma unroll
    for (int nt = 0; nt < 8; ++nt) {
        int col = nt * 16 + lm;
        float wa = aws[col], wd = awd[col];
#pragma unroll
        for (int r = 0; r < 4; ++r) {
            float v = acc[nt][r];
            h[(size_t)(m0 + lq * 4 + r) * OUT_DIM + col] = __float2half(v);
            sS[r] += v * wa;
            sD[r] += v * wd;
        }
    }
#pragma unroll
    for (int o = 1; o < 16; o <<= 1) {
#pragma unroll
        for (int r = 0; r < 4; ++r) {
            sS[r] += __shfl_xor(sS[r], o);
            sD[r] += __shfl_xor(sD[r], o);
        }
    }
    if (lm == 0) {
#pragma unroll
        for (int r = 0; r < 4; ++r) {
            int row = m0 + lq * 4 + r;
            as2[row] = sS[r];
            ad2[row] = sD[r];
        }
    }
}

// ================= fused softmax + aggregate, layer 1 (R7 version) =================
// wave per node; 2 rows per dwordx4 load: lanes 0-31 even edge, 32-63 odd edge,
// each lane owns 8 contiguous feats (16 B). LDS stages {row_byte_off, alpha} pairs.
__global__ __launch_bounds__(256) void aggregate1_fused(
        const int* __restrict__ rp, const int* __restrict__ cs,
        const __half* __restrict__ h1h, const float* __restrict__ as1,
        const float* __restrict__ ad1, const float* __restrict__ b1,
        __half* __restrict__ out1h) {
    __shared__ int2 stg[4][64][4];   // [wave][edge][head] = {row byte offset, alpha bits}
    const int wv = threadIdx.x >> 6, lane = threadIdx.x & 63;
    const int d = blockIdx.x * 4 + wv;
    const int e0 = rp[d], deg = rp[d + 1] - e0;  // deg >= 1 (self-loop)
    const float4 adv = ((const float4*)ad1)[d];
    const int half = lane >> 5, li = lane & 31;
    const int head = li >> 3;        // feats [li*8, li*8+8) all in head li>>3
    const int lbyte = li * 16;       // 8 fp16 = 16 B
    const char* hbase = (const char*)h1h;
    int2* sp = &stg[wv][0][0];
    float acc[8] = {0.f, 0.f, 0.f, 0.f, 0.f, 0.f, 0.f, 0.f};
    float4 dsum = make_float4(0.f, 0.f, 0.f, 0.f);
    for (int c0 = 0; c0 < deg; c0 += 64) {
        const int clen = min(64, deg - c0);
        int idx = c0 + lane;
        bool valid = idx < deg;
        int s = valid ? cs[e0 + idx] : 0;
        float4 av = ((const float4*)as1)[s];
        float x0 = valid ? expf(leaky(av.x + adv.x)) : 0.f;
        float x1 = valid ? expf(leaky(av.y + adv.y)) : 0.f;
        float x2 = valid ? expf(leaky(av.z + adv.z)) : 0.f;
        float x3 = valid ? expf(leaky(av.w + adv.w)) : 0.f;
        int off = valid ? (s << 9) : 0;   // row = 256 fp16 = 512 B
        ((int4*)sp)[lane * 2]     = make_int4(off, __float_as_int(x0), off, __float_as_int(x1));
        ((int4*)sp)[lane * 2 + 1] = make_int4(off, __float_as_int(x2), off, __float_as_int(x3));
        dsum.x += x0; dsum.y += x1; dsum.z += x2; dsum.w += x3;
        __builtin_amdgcn_wave_barrier();  // DS in-order per wave; block compiler reordering
        int j = 0;
        for (; j + 4 <= clen; j += 4) {
            int2 p0 = sp[(j + half) * 4 + head];
            int2 p1 = sp[(j + 2 + half) * 4 + head];
            h8 v0 = *(const h8*)(hbase + p0.x + lbyte);
            h8 v1 = *(const h8*)(hbase + p1.x + lbyte);
            float w0 = __int_as_float(p0.y), w1 = __int_as_float(p1.y);
#pragma unroll
            for (int f = 0; f < 8; ++f) acc[f] += (float)v0[f] * w0;
#pragma unroll
            for (int f = 0; f < 8; ++f) acc[f] += (float)v1[f] * w1;
        }
        for (; j < clen; j += 2) {
            int2 p0 = sp[(j + half) * 4 + head];
            h8 v0 = *(const h8*)(hbase + p0.x + lbyte);
            float w0 = __int_as_float(p0.y);
#pragma unroll
            for (int f = 0; f < 8; ++f) acc[f] += (float)v0[f] * w0;
        }
        __builtin_amdgcn_wave_barrier();
    }
    // combine even/odd halves (lane l + lane l^32 hold same feats)
#pragma unroll
    for (int f = 0; f < 8; ++f) acc[f] += __shfl_xor(acc[f], 32);
    // denominators over all 64 lanes
#pragma unroll
    for (int o = 32; o > 0; o >>= 1) {
        dsum.x += __shfl_xor(dsum.x, o); dsum.y += __shfl_xor(dsum.y, o);
        dsum.z += __shfl_xor(dsum.z, o); dsum.w += __shfl_xor(dsum.w, o);
    }
    float den = (head == 0) ? dsum.x : (head == 1) ? dsum.y : (head == 2) ? dsum.z : dsum.w;
    if (half == 0) {
        float inv = 1.0f / (den + 1e-16f);
        float4 bA = ((const float4*)b1)[li * 2];
        float4 bB = ((const float4*)b1)[li * 2 + 1];
        h8 o;
        o[0] = (_Float16)elu(acc[0] * inv + bA.x);
        o[1] = (_Float16)elu(acc[1] * inv + bA.y);
        o[2] = (_Float16)elu(acc[2] * inv + bA.z);
        o[3] = (_Float16)elu(acc[3] * inv + bA.w);
        o[4] = (_Float16)elu(acc[4] * inv + bB.x);
        o[5] = (_Float16)elu(acc[5] * inv + bB.y);
        o[6] = (_Float16)elu(acc[6] * inv + bB.z);
        o[7] = (_Float16)elu(acc[7] * inv + bB.w);
        *(h8*)((char*)out1h + (size_t)d * 512 + lbyte) = o;
    }
}

// ================= fused softmax + aggregate + bias + L2-normalize, layer 2 =================
// wave per node; 4 rows per dwordx4 load (16 lanes x 16 B per row).
__global__ __launch_bounds__(256) void aggregate2_fused(
        const int* __restrict__ rp, const int* __restrict__ cs,
        const __half* __restrict__ h2h, const float* __restrict__ as2,
        const float* __restrict__ ad2, const float* __restrict__ b2,
        float* __restrict__ out) {
    __shared__ int2 stg[4][64];      // [wave][edge] = {row byte offset, alpha bits}
    const int wv = threadIdx.x >> 6, lane = threadIdx.x & 63;
    const int d = blockIdx.x * 4 + wv;
    const int e0 = rp[d], deg = rp[d + 1] - e0;
    const float adv = ad2[d];
    const int q = lane >> 4, li = lane & 15;
    const int lbyte = li * 16;       // 8 fp16
    const char* hbase = (const char*)h2h;
    float acc[8] = {0.f, 0.f, 0.f, 0.f, 0.f, 0.f, 0.f, 0.f};
    float dsum = 0.f;
    for (int c0 = 0; c0 < deg; c0 += 64) {
        const int clen = min(64, deg - c0);
        int idx = c0 + lane;
        bool valid = idx < deg;
        int s = valid ? cs[e0 + idx] : 0;
        float x = valid ? expf(leaky(as2[s] + adv)) : 0.f;
        stg[wv][lane] = make_int2(valid ? (s << 8) : 0, __float_as_int(x));  // row = 256 B
        dsum += x;
        __builtin_amdgcn_wave_barrier();
        int j = 0;
        for (; j + 8 <= clen; j += 8) {
            int2 p0 = stg[wv][j + q];
            int2 p1 = stg[wv][j + 4 + q];
            h8 v0 = *(const h8*)(hbase + p0.x + lbyte);
            h8 v1 = *(const h8*)(hbase + p1.x + lbyte);
            float w0 = __int_as_float(p0.y), w1 = __int_as_float(p1.y);
#pragma unroll
            for (int f = 0; f < 8; ++f) acc[f] += (float)v0[f] * w0;
#pragma unroll
            for (int f = 0; f < 8; ++f) acc[f] += (float)v1[f] * w1;
        }
        for (; j < clen; j += 4) {
            int2 p0 = stg[wv][j + q];
            h8 v0 = *(const h8*)(hbase + p0.x + lbyte);
            float w0 = __int_as_float(p0.y);
#pragma unroll
            for (int f = 0; f < 8; ++f) acc[f] += (float)v0[f] * w0;
        }
        __builtin_amdgcn_wave_barrier();
    }
#pragma unroll
    for (int f = 0; f < 8; ++f) {
        acc[f] += __shfl_xor(acc[f], 16);
        acc[f] += __shfl_xor(acc[f], 32);
    }
#pragma unroll
    for (int o = 32; o > 0; o >>= 1) dsum += __shfl_xor(dsum, o);
    if (q == 0) {
        float inv = 1.0f / (dsum + 1e-16f);
        float4 bA = ((const float4*)b2)[li * 2];
        float4 bB = ((const float4*)b2)[li * 2 + 1];
        float v0 = acc[0] * inv + bA.x, v1 = acc[1] * inv + bA.y;
        float v2 = acc[2] * inv + bA.z, v3 = acc[3] * inv + bA.w;
        float v4 = acc[4] * inv + bB.x, v5 = acc[5] * inv + bB.y;
        float v6 = acc[6] * inv + bB.z, v7 = acc[7] * inv + bB.w;
        float ss = v0 * v0 + v1 * v1 + v2 * v2 + v3 * v3 +
                   v4 * v4 + v5 * v5 + v6 * v6 + v7 * v7;
#pragma unroll
        for (int o = 1; o < 16; o <<= 1) ss += __shfl_xor(ss, o);  // lanes 0-15 group
        float sc = 1.0f / fmaxf(sqrtf(ss), 1e-12f);
        float4* orow = (float4*)((char*)out + (size_t)d * 512 + li * 32);
        orow[0] = make_float4(v0 * sc, v1 * sc, v2 * sc, v3 * sc);
        orow[1] = make_float4(v4 * sc, v5 * sc, v6 * sc, v7 * sc);
    }
}

extern "C" void kernel_launch(void* const* d_in, const int* in_sizes, int n_in,
                              void* d_out, int out_size, void* d_ws, size_t ws_size,
                              hipStream_t stream) {
    const float* x     = (const float*)d_in[0];
    const int*   edge  = (const int*)d_in[1];
    const int*   src   = edge;
    const int*   dst   = edge + N_EDGES;
    const float* W1    = (const float*)d_in[2];
    const float* aw_s1 = (const float*)d_in[3];
    const float* aw_d1 = (const float*)d_in[4];
    const float* b1    = (const float*)d_in[5];
    const float* W2    = (const float*)d_in[6];
    const float* aw_s2 = (const float*)d_in[7];
    const float* aw_d2 = (const float*)d_in[8];
    const float* b2    = (const float*)d_in[9];
    float* out = (float*)d_out;

    // ---- workspace layout: small control buffers first, big streams last ----
    char* ws = (char*)d_ws;
    size_t off = 0;
    auto alloc = [&](size_t bytes) {
        void* p = ws + off;
        off += (bytes + 255) & ~(size_t)255;
        return p;
    };
    int*    col_src = (int*)alloc((size_t)ET * 4);                  // 3.4 MB
    int*    rp     = (int*)alloc((size_t)(N_NODES + 1) * 4);
    int*    cursor = (int*)alloc((size_t)N_NODES * 4);
    int*    cnt    = (int*)alloc((size_t)N_NODES * 4);
    int*    lscan  = (int*)alloc((size_t)NSCB * SCAN_B * 4);
    int*    bsum   = (int*)alloc((size_t)NSCB * 4);
    float*  as1    = (float*)alloc((size_t)N_NODES * HEADS * 4);
    float*  ad1    = (float*)alloc((size_t)N_NODES * HEADS * 4);
    float*  as2    = (float*)alloc((size_t)N_NODES * 4);
    float*  ad2    = (float*)alloc((size_t)N_NODES * 4);
    __half* w1t    = (__half*)alloc((size_t)IN_DIM * C1 * 2);
    __half* w2t    = (__half*)alloc((size_t)C1 * OUT_DIM * 2);
    __half* h1h    = (__half*)alloc((size_t)N_NODES * C1 * 2);      // 25.6 MB (reused as h2h)
    __half* out1h  = (__half*)alloc((size_t)N_NODES * C1 * 2);      // 25.6 MB
    __half* h2h    = h1h;  // layer-1 projection dead after aggregate1
    const size_t ws_used = off;

    // Reproduce call-1 initial state every call (harness re-poisons ws with 0xAA).
    hipMemsetAsync(d_ws, 0, ws_used, stream);

    const int egrid = (ET + 255) / 256;

    // ---- prep (weight transpose + histogram) + CSR build ----
    prep_kernel<<<1024, 256, 0, stream>>>(W1, W2, dst, w1t, w2t, cnt);
    scan_local<<<NSCB, SCAN_B, 0, stream>>>(cnt, lscan, bsum);
    scan_bsum<<<1, 64, 0, stream>>>(bsum);
    scan_final<<<NSCB, SCAN_B, 0, stream>>>(cnt, lscan, bsum, rp, cursor);
    scatter_kernel<<<egrid, 256, 0, stream>>>(src, dst, cursor, col_src);

    // ---- layer 1 ----
    gemm1_mfma<<<(MTILES + 3) / 4, 256, 0, stream>>>(x, w1t, aw_s1, aw_d1, h1h, as1, ad1);
    aggregate1_fused<<<N_NODES / 4, 256, 0, stream>>>(rp, col_src, h1h, as1, ad1, b1, out1h);

    // ---- layer 2 ----
    gemm2_mfma<<<(MTILES + 3) / 4, 256, 0, stream>>>(out1h, w2t, aw_s2, aw_d2, h2h, as2, ad2);
    aggregate2_fused<<<N_NODES / 4, 256, 0, stream>>>(rp, col_src, h2h, as2, ad2, b2, out);
}